// Round 15
// baseline (77.400 us; speedup 1.0000x reference)
//
#include <hip/hip_runtime.h>
#include <math.h>

#define LBL   8
#define DIM   96
#define PLANE (DIM*DIM)          // 9216
#define NVOX  (DIM*DIM*DIM)      // 884736
#define GD0 14
#define GD1 14
#define GD2 14
#define GD3 10
#define GSIZE (GD0*GD1*GD2*GD3)  // 27440
#define ST0 1960
#define ST1 140
#define ST2 10
#define CH  12                   // padded channel stride (9 used)
#define NBLK 12
#define NBLKS (NBLK*NBLK*NBLK)   // 1728
#define PART 720                 // per-block splat footprint: 8 corners x 10 bins x 9 ch
#define GOUT (GSIZE*9)           // 246960 real grid scalars
#define SUP 513                  // padded sU stride in halves (bank-conflict fix)
#define ROW8 (DIM/8)             // 12 half8 per row
#define PLANE8 (PLANE/8)         // 1152 half8 per z-slice
#define VOL8 (NVOX/8)            // 110592 half8 per label
#define XY_BLOCKS 768            // 8 labels x 96 z
#define GVB ((GOUT + 255)/256)   // 965 gather/blur virtual blocks
#define Z_BLOCKS 864

typedef _Float16 half8 __attribute__((ext_vector_type(8)));

__device__ inline half8 h8zero() {
    half8 v;
    #pragma unroll
    for (int e = 0; e < 8; ++e) v[e] = (_Float16)0.f;
    return v;
}

// normalized Gaussian weights, sigma=3, radius=9 (by |t|)
__constant__ float GW[10] = {
    0.13317604f, 0.12597912f, 0.10663904f, 0.08077540f, 0.05475300f,
    0.03320771f, 0.01802341f, 0.00875346f, 0.00380423f, 0.00147945f
};

// ---------------------------------------------------------------------------
// Kernel A: per-voxel softmax + 4-D bilateral-grid splat.
// Writes lnq = (u-m) - ln(sum) fp16. Stage C writes the 720-float footprint
// to a PRIVATE part slot (non-atomic, coalesced): no grid zeroing, no atomics,
// fully deterministic. Gather happens in the next dispatch's helper blocks.
// ---------------------------------------------------------------------------
__global__ __launch_bounds__(512)
void k_softmax_splat(const float* __restrict__ U, const float* __restrict__ img,
                     _Float16* __restrict__ lnq, float* __restrict__ part)
{
    __shared__ float sF[512];
    __shared__ __align__(16) unsigned char uball[2880 * 4];  // max(sU 9234B, sB 11520B)
    __shared__ _Float16 sA[64*180];   // row*180 + k2*90 + g*9 + c

    _Float16* sU = (_Float16*)uball;  // [9*SUP] halves, dead after stage A
    float*    sB = (float*)uball;     // [8*360] floats, written in stage B

    const int tid = threadIdx.x;
    const int bid0 = blockIdx.x;
    const int bid = (bid0 & 7) * (NBLKS >> 3) + (bid0 >> 3);  // XCD-chunk swizzle
    const int bx = bid % NBLK;
    const int by = (bid / NBLK) % NBLK;
    const int bz = bid / (NBLK*NBLK);

    const int lx = tid & 7;
    const int ly = (tid >> 3) & 7;
    const int lz = tid >> 6;

    const int x = bx*8 + lx;
    const int y = by*8 + ly;
    const int z = bz*8 + lz;
    const int vox = z * PLANE + y * DIM + x;

    // ---- phase 0: softmax, write lnq (fp16), stage q in LDS ----
    {
        float t[LBL], e[LBL];
        float m = -1e30f;
        #pragma unroll
        for (int l = 0; l < LBL; ++l) { t[l] = U[l*NVOX + vox]; m = fmaxf(m, t[l]); }
        float ssum = 0.f;
        #pragma unroll
        for (int l = 0; l < LBL; ++l) { t[l] -= m; e[l] = __expf(t[l]); ssum += e[l]; }
        const float inv  = 1.f / ssum;
        const float logs = __logf(ssum);
        #pragma unroll
        for (int l = 0; l < LBL; ++l) {
            lnq[l*NVOX + vox] = (_Float16)(t[l] - logs);
            sU[l*SUP + tid]   = (_Float16)(e[l] * inv);
        }
        sU[8*SUP + tid] = (_Float16)1.0f;  // homogeneous channel
        sF[tid] = img[vox] * 8.0f;         // f = img/BETA, in [0,8)
    }
    __syncthreads();

    // ---- stage A: x-reduce. thread = (row, k2, cgrp) ----
    {
        const int cgrp = tid & 3;          // ch groups {0,1},{2,3},{4,5},{6,7,8}
        const int k2   = (tid >> 2) & 1;
        const int row  = tid >> 3;         // 0..63  (ly + 8*lz)
        const int cb   = cgrp * 2;

        float bins[10][3];
        #pragma unroll
        for (int g = 0; g < 10; ++g) { bins[g][0]=0.f; bins[g][1]=0.f; bins[g][2]=0.f; }

        for (int vx = 0; vx < 8; ++vx) {
            const int vi = row*8 + vx;
            const float f  = sF[vi];
            const float wx = k2 ? (float)vx*0.125f : 1.f - (float)vx*0.125f;
            const float u0 = (float)sU[cb*SUP + vi];
            const float u1 = (float)sU[(cb+1)*SUP + vi];
            const float u2 = (float)sU[8*SUP + vi];   // only meaningful for cgrp==3
            #pragma unroll
            for (int g = 0; g < 10; ++g) {
                float w = fmaxf(1.f - fabsf(f - (float)g), 0.f) * wx;
                bins[g][0] += w*u0; bins[g][1] += w*u1; bins[g][2] += w*u2;
            }
        }
        _Float16* pA = sA + row*180 + k2*90;
        #pragma unroll
        for (int g = 0; g < 10; ++g) {
            pA[g*9 + cb]     = (_Float16)bins[g][0];
            pA[g*9 + cb + 1] = (_Float16)bins[g][1];
            if (cgrp == 3) pA[g*9 + 8] = (_Float16)bins[g][2];
        }
    }
    __syncthreads();   // sU dead from here; sB may reuse its storage

    // ---- stage B: y-reduce. thread = (lz, j2, k2, c), 288 active ----
    if (tid < 288) {
        const int c   = tid % 9;
        const int k2  = (tid / 9) & 1;
        const int j2  = (tid / 18) & 1;
        const int lzo = tid / 36;          // 0..7
        float S[10];
        #pragma unroll
        for (int g = 0; g < 10; ++g) S[g] = 0.f;
        for (int ly2 = 0; ly2 < 8; ++ly2) {
            const float wy = j2 ? (float)ly2*0.125f : 1.f - (float)ly2*0.125f;
            const _Float16* pA = sA + (lzo*8 + ly2)*180 + k2*90;
            #pragma unroll
            for (int g = 0; g < 10; ++g) S[g] += wy * (float)pA[g*9 + c];
        }
        float* pB = sB + lzo*360 + j2*180 + k2*90;
        #pragma unroll
        for (int g = 0; g < 10; ++g) pB[g*9 + c] = S[g];
    }
    __syncthreads();

    // ---- stage C: z-reduce -> private part slot (coalesced, non-atomic) ----
    for (int item = tid; item < PART; item += 512) {
        const int t  = item / 90;          // corner: i2*4 + j2*2 + k2
        const int gc = item % 90;
        const int i2 = t >> 2, j2 = (t >> 1) & 1, k2 = t & 1;
        float acc = 0.f;
        #pragma unroll
        for (int lzo = 0; lzo < 8; ++lzo) {
            const float wz = i2 ? (float)lzo*0.125f : 1.f - (float)lzo*0.125f;
            acc += wz * sB[lzo*360 + j2*180 + k2*90 + gc];
        }
        part[(size_t)bid*PART + item] = acc;
    }
}

// ---------------------------------------------------------------------------
// Dispatch 2: blocks [0, XY_BLOCKS) Gaussian x+y slice pass (q = exp(lnq));
// blocks [XY_BLOCKS, XY_BLOCKS+GVB): gather part -> gridA (R2's k_reduce).
// Both depend only on k_softmax_splat.
// ---------------------------------------------------------------------------
__global__ __launch_bounds__(256)
void k_xy_gather(const half8* __restrict__ lnq, half8* __restrict__ dst,
                 const float* __restrict__ part, float* __restrict__ grid)
{
    __shared__ _Float16 sIn[PLANE];
    __shared__ _Float16 sX[PLANE];

    const int tid = threadIdx.x;

    if (blockIdx.x >= XY_BLOCKS) {
        // ---- gather per-cell partials from <=8 contributing blocks ----
        const int item = (blockIdx.x - XY_BLOCKS)*256 + tid;
        if (item >= GOUT) return;
        const int c    = item % 9;
        const int cell = item / 9;
        const int gz = cell / ST0;
        int r = cell % ST0;
        const int gy = r / ST1;  r %= ST1;
        const int gx = r / ST2;
        const int g  = r % ST2;
        float acc = 0.f;
        #pragma unroll
        for (int t = 0; t < 8; ++t) {
            const int i2 = t >> 2, j2 = (t >> 1) & 1, k2 = t & 1;
            const int bz = gz - i2, by = gy - j2, bx = gx - k2;
            if ((unsigned)bz < (unsigned)NBLK && (unsigned)by < (unsigned)NBLK &&
                (unsigned)bx < (unsigned)NBLK)
                acc += part[(size_t)((bz*NBLK + by)*NBLK + bx)*PART + t*90 + g*9 + c];
        }
        grid[cell*CH + c] = acc;
        return;
    }

    // ---- Gaussian x+y over one (label,z) slice held in LDS ----
    half8* sIn8 = (half8*)sIn;
    half8* sX8  = (half8*)sX;
    const size_t base8 = (size_t)blockIdx.x * PLANE8;

    // stage: q = exp(lnq)
    for (int i = tid; i < PLANE8; i += 256) {
        const half8 v = lnq[base8 + i];
        half8 w;
        #pragma unroll
        for (int e = 0; e < 8; ++e) w[e] = (_Float16)__expf((float)v[e]);
        sIn8[i] = w;
    }
    __syncthreads();

    // x-blur: item = row*6 + seg; outputs x = 16*seg .. 16*seg+15
    for (int it = tid; it < 576; it += 256) {
        const int seg = it % 6;
        const int row = it / 6;
        float w[48];
        #pragma unroll
        for (int k = 0; k < 6; ++k) {
            const int j8 = 2*seg - 2 + k;
            half8 v = h8zero();
            if (j8 >= 0 && j8 < ROW8) v = sIn8[row*ROW8 + j8];
            #pragma unroll
            for (int e = 0; e < 8; ++e) w[k*8 + e] = (float)v[e];
        }
        half8 o0 = h8zero(), o1 = h8zero();
        #pragma unroll
        for (int i = 0; i < 16; ++i) {
            float acc = 0.f;
            #pragma unroll
            for (int t = -9; t <= 9; ++t) acc += GW[t < 0 ? -t : t] * w[i + 16 + t];
            if (i < 8) o0[i] = (_Float16)acc; else o1[i - 8] = (_Float16)acc;
        }
        sX8[row*ROW8 + 2*seg]     = o0;
        sX8[row*ROW8 + 2*seg + 1] = o1;
    }
    __syncthreads();

    // y-blur: item = yseg*12 + x8; outputs y = 4*yseg .. 4*yseg+3
    for (int it = tid; it < 288; it += 256) {
        const int x8   = it % ROW8;
        const int yseg = it / ROW8;
        const int ct = yseg * 4;
        float acc[4][8];
        #pragma unroll
        for (int k = 0; k < 4; ++k)
            #pragma unroll
            for (int e = 0; e < 8; ++e) acc[k][e] = 0.f;
        #pragma unroll
        for (int jj = 0; jj < 22; ++jj) {
            const int j = ct - 9 + jj;
            if (j < 0 || j >= DIM) continue;
            const half8 v = sX8[j*ROW8 + x8];
            float f[8];
            #pragma unroll
            for (int e = 0; e < 8; ++e) f[e] = (float)v[e];
            #pragma unroll
            for (int k = 0; k < 4; ++k) {
                const int d = jj - 9 - k;
                if (d >= -9 && d <= 9) {
                    const float wgt = GW[d < 0 ? -d : d];
                    #pragma unroll
                    for (int e = 0; e < 8; ++e) acc[k][e] += wgt * f[e];
                }
            }
        }
        #pragma unroll
        for (int k = 0; k < 4; ++k) {
            half8 o;
            #pragma unroll
            for (int e = 0; e < 8; ++e) o[e] = (_Float16)acc[k][e];
            dst[base8 + (ct + k)*ROW8 + x8] = o;
        }
    }
}

// ---------------------------------------------------------------------------
// Dispatch 3: blocks [0, Z_BLOCKS) Gaussian z-pass (g1 -> sp); blocks
// [Z_BLOCKS, Z_BLOCKS+GVB): 81-tap 4-D grid blur (gridA -> gridB).
// z depends on xy (prev dispatch); blur depends on gather (prev dispatch).
// ---------------------------------------------------------------------------
__global__ __launch_bounds__(256)
void k_z_blur(const half8* __restrict__ src, half8* __restrict__ dst,
              const float* __restrict__ gsrc, float* __restrict__ gdst)
{
    const int tid = threadIdx.x;

    if (blockIdx.x >= Z_BLOCKS) {
        // ---- 81-tap 4-D [1,2,1]/4 blur over the L2-resident grid ----
        const int item = (blockIdx.x - Z_BLOCKS)*256 + tid;
        if (item >= GOUT) return;
        const int c    = item % 9;
        const int cell = item / 9;
        const int gz = cell / ST0;
        int r = cell % ST0;
        const int gy = r / ST1;  r %= ST1;
        const int gx = r / ST2;
        const int g  = r % ST2;

        const int crd[4] = {gz, gy, gx, g};
        const int ext[4] = {GD0, GD1, GD2, GD3};
        const int str[4] = {ST0, ST1, ST2, 1};
        float wa[4][3];
        int   oa[4][3];
        #pragma unroll
        for (int ax = 0; ax < 4; ++ax)
            #pragma unroll
            for (int dd = 0; dd < 3; ++dd) {
                const int cc = crd[ax] + dd - 1;
                const bool ok = (cc >= 0 && cc < ext[ax]);
                wa[ax][dd] = ok ? (dd == 1 ? 0.5f : 0.25f) : 0.f;
                oa[ax][dd] = ok ? (dd - 1) * str[ax] : 0;
            }

        float acc = 0.f;
        #pragma unroll
        for (int a = 0; a < 3; ++a) {
            const float w0 = wa[0][a];
            #pragma unroll
            for (int b = 0; b < 3; ++b) {
                const float w1 = w0 * wa[1][b];
                #pragma unroll
                for (int d2 = 0; d2 < 3; ++d2) {
                    const float w2 = w1 * wa[2][d2];
                    const int ob = oa[0][a] + oa[1][b] + oa[2][d2];
                    #pragma unroll
                    for (int e = 0; e < 3; ++e)
                        acc += w2 * wa[3][e] * gsrc[(cell + ob + oa[3][e])*CH + c];
                }
            }
        }
        gdst[cell*CH + c] = acc;
        return;
    }

    // ---- Gaussian z-pass: thread owns 8 x-halves x 4 outputs along z ----
    const int bid = blockIdx.x;
    const int swz = (bid & 7) * (Z_BLOCKS >> 3) + (bid >> 3);
    const int u = swz * 256 + tid;

    const int x8 = u % ROW8;
    const int yy = (u / ROW8) % DIM;
    const int ztl = u / (ROW8 * DIM);       // zt + 24*l
    const int zt = ztl % (DIM/4);
    const int l  = ztl / (DIM/4);
    const int base8 = l * VOL8 + yy * ROW8 + x8;
    const int ct = zt * 4;

    float acc[4][8];
    #pragma unroll
    for (int k = 0; k < 4; ++k)
        #pragma unroll
        for (int e = 0; e < 8; ++e) acc[k][e] = 0.f;

    #pragma unroll
    for (int jj = 0; jj < 22; ++jj) {
        const int j = ct - 9 + jj;
        if (j < 0 || j >= DIM) continue;
        const half8 v = src[base8 + j*PLANE8];
        float f[8];
        #pragma unroll
        for (int e = 0; e < 8; ++e) f[e] = (float)v[e];
        #pragma unroll
        for (int k = 0; k < 4; ++k) {
            const int d = jj - 9 - k;
            if (d >= -9 && d <= 9) {
                const float wgt = GW[d < 0 ? -d : d];
                #pragma unroll
                for (int e = 0; e < 8; ++e) acc[k][e] += wgt * f[e];
            }
        }
    }
    #pragma unroll
    for (int k = 0; k < 4; ++k) {
        half8 o;
        #pragma unroll
        for (int e = 0; e < 8; ++e) o[e] = (_Float16)acc[k][e];
        dst[base8 + (ct + k)*PLANE8] = o;
    }
}

// ---------------------------------------------------------------------------
// Final: block = 32x16x1 voxels (512 thr, z BLOCK-UNIFORM).
// LDS-staged z-prereduced grid footprint; reads lnq fp16 + sp fp16 coalesced;
// out = softmax(lnq + Qp) == softmax(U + Qp).
// ---------------------------------------------------------------------------
__global__ __launch_bounds__(512)
void k_final(const _Float16* __restrict__ lnq, const _Float16* __restrict__ sp,
             const float* __restrict__ grid, const float* __restrict__ img,
             const float* __restrict__ Cm, const float* __restrict__ Sw,
             const float* __restrict__ Bw, float* __restrict__ out)
{
    __shared__ float sm[128];
    __shared__ __align__(16) float sG[1800];   // [yc3][xc5][g10][c12]

    const int tid = threadIdx.x;
    if (tid < 64) {
        const int i = tid >> 3, j = tid & 7;
        float cs = 0.f, cb = 0.f;
        #pragma unroll
        for (int k = 0; k < 8; ++k) {
            cs += Cm[i*8 + k] * Sw[k*8 + j];
            cb += Cm[i*8 + k] * Bw[k*8 + j];
        }
        sm[tid] = cs;
        sm[64 + tid] = cb;
    }

    const int bid0 = blockIdx.x;
    const int bid = (bid0 & 7) * (1728 >> 3) + (bid0 >> 3);   // XCD-chunk swizzle
    const int bxi = bid % 3;
    const int byi = (bid / 3) % 6;
    const int z   = bid / 18;            // 0..95 (uniform per block)

    const int zc0 = z >> 3;
    const float fz = (float)(z & 7) * 0.125f;

    // stage z-prereduced grid footprint (grid is L2-resident)
    for (int item = tid; item < 1800; item += 512) {
        const int c    = item % 12;
        const int cell = item / 12;        // yc*50 + xc*10 + g
        const int g  = cell % 10;
        const int xc = (cell / 10) % 5;
        const int yc = cell / 50;
        const int cellA = zc0*ST0 + (byi*2 + yc)*ST1 + (bxi*4 + xc)*ST2 + g;
        sG[item] = (1.f - fz)*grid[cellA*CH + c] + fz*grid[(cellA + ST0)*CH + c];
    }
    __syncthreads();

    const int lx  = tid & 31;
    const int lyt = tid >> 5;            // 0..15
    const int x = bxi*32 + lx;
    const int y = byi*16 + lyt;
    const int vox = z*PLANE + y*DIM + x;

    const float f = img[vox] * 8.0f;
    int li = (int)floorf(f);
    li = li < 0 ? 0 : (li > 8 ? 8 : li);
    const float fi = f - (float)li;
    const float fy = (float)(y & 7) * 0.125f;
    const float fx = (float)(x & 7) * 0.125f;
    const float wyv[2] = {1.f - fy, fy};
    const float wxv[2] = {1.f - fx, fx};
    const float wiv[2] = {1.f - fi, fi};
    const int ycb = lyt >> 3;            // 0..1
    const int xcb = lx >> 3;             // 0..3

    float acc[9];
    #pragma unroll
    for (int c = 0; c < 9; ++c) acc[c] = 0.f;

    #pragma unroll
    for (int j2 = 0; j2 < 2; ++j2)
    #pragma unroll
    for (int k2 = 0; k2 < 2; ++k2) {
        const float wsp = wyv[j2] * wxv[k2];
        const int base = (((ycb + j2)*5 + (xcb + k2))*10 + li)*12;
        #pragma unroll
        for (int m2 = 0; m2 < 2; ++m2) {
            const float w = wsp * wiv[m2];
            const float* p = &sG[base + m2*12];
            const float4 p0 = *reinterpret_cast<const float4*>(p);
            const float4 p1 = *reinterpret_cast<const float4*>(p + 4);
            acc[0] += w * p0.x; acc[1] += w * p0.y; acc[2] += w * p0.z; acc[3] += w * p0.w;
            acc[4] += w * p1.x; acc[5] += w * p1.y; acc[6] += w * p1.z; acc[7] += w * p1.w;
            acc[8] += w * p[8];
        }
    }
    const float dinv = 1.f / (acc[8] + 1e-8f);

    float spv[LBL], lq[LBL];
    #pragma unroll
    for (int l = 0; l < LBL; ++l) {
        spv[l] = (float)sp[(size_t)l*NVOX + vox];
        lq[l]  = (float)lnq[(size_t)l*NVOX + vox];
    }

    float v[LBL];
    float mx = -1e30f;
    #pragma unroll
    for (int i = 0; i < LBL; ++i) {
        float t = 0.f;
        #pragma unroll
        for (int l = 0; l < LBL; ++l)
            t += sm[i*8 + l] * spv[l] + sm[64 + i*8 + l] * (acc[l] * dinv);
        v[i] = lq[i] + t;
        mx = fmaxf(mx, v[i]);
    }
    float ssum = 0.f;
    #pragma unroll
    for (int i = 0; i < LBL; ++i) { v[i] = __expf(v[i] - mx); ssum += v[i]; }
    const float inv = 1.f / ssum;
    #pragma unroll
    for (int i = 0; i < LBL; ++i) out[i*NVOX + vox] = v[i] * inv;
}

extern "C" void kernel_launch(void* const* d_in, const int* in_sizes, int n_in,
                              void* d_out, int out_size, void* d_ws, size_t ws_size,
                              hipStream_t stream)
{
    const float* U   = (const float*)d_in[0];
    const float* img = (const float*)d_in[1];
    const float* Sw  = (const float*)d_in[2];
    const float* Bw  = (const float*)d_in[3];
    const float* Cm  = (const float*)d_in[4];
    float* out = (float*)d_out;

    _Float16* qh  = (_Float16*)d_ws;                       // lnq: 8*NVOX halves
    _Float16* g1h = qh  + (size_t)LBL * NVOX;              // xy-out: 8*NVOX halves
    _Float16* g2h = g1h + (size_t)LBL * NVOX;              // sp: 8*NVOX halves
    float* gridA  = (float*)(g2h + (size_t)LBL * NVOX);    // GSIZE*CH floats
    float* gridB  = gridA + (size_t)GSIZE * CH;            // GSIZE*CH floats
    float* part   = gridB + (size_t)GSIZE * CH;            // NBLKS*PART floats

    k_softmax_splat<<<NBLKS, 512, 0, stream>>>(U, img, qh, part);

    k_xy_gather<<<XY_BLOCKS + GVB, 256, 0, stream>>>(
        (const half8*)qh, (half8*)g1h, part, gridA);

    k_z_blur<<<Z_BLOCKS + GVB, 256, 0, stream>>>(
        (const half8*)g1h, (half8*)g2h, gridA, gridB);

    k_final<<<1728, 512, 0, stream>>>(qh, (const _Float16*)g2h,
                                      gridB, img, Cm, Sw, Bw, out);
}

// Round 16
// 75.359 us; speedup vs baseline: 1.0271x; 1.0271x over previous
//
#include <hip/hip_runtime.h>
#include <math.h>

#define LBL   8
#define DIM   96
#define PLANE (DIM*DIM)          // 9216
#define NVOX  (DIM*DIM*DIM)      // 884736
#define GD0 14
#define GD1 14
#define GD2 14
#define GD3 10
#define GSIZE (GD0*GD1*GD2*GD3)  // 27440
#define ST0 1960
#define ST1 140
#define ST2 10
#define CH  12                   // padded channel stride (9 used)
#define NBLK 12
#define NBLKS (NBLK*NBLK*NBLK)   // 1728
#define PART 720                 // per-block splat footprint: 8 corners x 10 bins x 9 ch
#define GOUT (GSIZE*9)           // 246960 real grid scalars
#define SUP 520                  // sU plane stride in halves: 1040B = 16B-aligned planes,
                                 // cgrp planes at bank shifts {0,8,16,24} -> b128 conflict-free
#define ROW8 (DIM/8)             // 12 half8 per row
#define PLANE8 (PLANE/8)         // 1152 half8 per z-slice
#define VOL8 (NVOX/8)            // 110592 half8 per label
#define XY_BLOCKS 768            // 8 labels x 96 z
#define GVB ((GOUT + 255)/256)   // 965 gather/blur virtual blocks
#define Z_BLOCKS 864

typedef _Float16 half8 __attribute__((ext_vector_type(8)));

__device__ inline half8 h8zero() {
    half8 v;
    #pragma unroll
    for (int e = 0; e < 8; ++e) v[e] = (_Float16)0.f;
    return v;
}

// normalized Gaussian weights, sigma=3, radius=9 (by |t|)
__constant__ float GW[10] = {
    0.13317604f, 0.12597912f, 0.10663904f, 0.08077540f, 0.05475300f,
    0.03320771f, 0.01802341f, 0.00875346f, 0.00380423f, 0.00147945f
};

// ---------------------------------------------------------------------------
// Kernel A: per-voxel softmax + 4-D bilateral-grid splat.
// lnq = (u-m) - ln(sum) fp16; stage C -> private part slot (no atomics).
// R14: stage A reads sU as half8 (1 ds_read_b128 per channel instead of 8
// ds_read_u16) and sF as 2x float4 — per-thread LDS ops 32 -> 5; the LDS
// port is CU-shared so this cuts ~3.5 us of serialized issue.
// ---------------------------------------------------------------------------
__global__ __launch_bounds__(512)
void k_softmax_splat(const float* __restrict__ U, const float* __restrict__ img,
                     _Float16* __restrict__ lnq, float* __restrict__ part)
{
    __shared__ __align__(16) float sF[512];
    __shared__ __align__(16) unsigned char uball[11520];  // max(sU 9360B, sB 11520B)
    __shared__ _Float16 sA[64*180];   // row*180 + k2*90 + g*9 + c

    _Float16* sU = (_Float16*)uball;  // [9*SUP] halves, dead after stage A
    float*    sB = (float*)uball;     // [8*360] floats, written in stage B

    const int tid = threadIdx.x;
    const int bid0 = blockIdx.x;
    const int bid = (bid0 & 7) * (NBLKS >> 3) + (bid0 >> 3);  // XCD-chunk swizzle
    const int bx = bid % NBLK;
    const int by = (bid / NBLK) % NBLK;
    const int bz = bid / (NBLK*NBLK);

    const int lx = tid & 7;
    const int ly = (tid >> 3) & 7;
    const int lz = tid >> 6;

    const int x = bx*8 + lx;
    const int y = by*8 + ly;
    const int z = bz*8 + lz;
    const int vox = z * PLANE + y * DIM + x;

    // ---- phase 0: softmax, write lnq (fp16), stage q in LDS ----
    {
        float t[LBL], e[LBL];
        float m = -1e30f;
        #pragma unroll
        for (int l = 0; l < LBL; ++l) { t[l] = U[l*NVOX + vox]; m = fmaxf(m, t[l]); }
        float ssum = 0.f;
        #pragma unroll
        for (int l = 0; l < LBL; ++l) { t[l] -= m; e[l] = __expf(t[l]); ssum += e[l]; }
        const float inv  = 1.f / ssum;
        const float logs = __logf(ssum);
        #pragma unroll
        for (int l = 0; l < LBL; ++l) {
            lnq[l*NVOX + vox] = (_Float16)(t[l] - logs);
            sU[l*SUP + tid]   = (_Float16)(e[l] * inv);
        }
        sU[8*SUP + tid] = (_Float16)1.0f;  // homogeneous channel
        sF[tid] = img[vox] * 8.0f;         // f = img/BETA, in [0,8)
    }
    __syncthreads();

    // ---- stage A: x-reduce. thread = (row, k2, cgrp), vector LDS loads ----
    {
        const int cgrp = tid & 3;          // ch groups {0,1},{2,3},{4,5},{6,7,8}
        const int k2   = (tid >> 2) & 1;
        const int row  = tid >> 3;         // 0..63  (ly + 8*lz)
        const int cb   = cgrp * 2;

        const half8 U0 = ((const half8*)(sU + cb*SUP))[row];
        const half8 U1 = ((const half8*)(sU + (cb+1)*SUP))[row];
        const half8 U2 = ((const half8*)(sU + 8*SUP))[row];  // used by cgrp==3
        const float4 F0 = ((const float4*)sF)[row*2];
        const float4 F1 = ((const float4*)sF)[row*2 + 1];
        const float fv[8] = {F0.x, F0.y, F0.z, F0.w, F1.x, F1.y, F1.z, F1.w};

        float bins[10][3];
        #pragma unroll
        for (int g = 0; g < 10; ++g) { bins[g][0]=0.f; bins[g][1]=0.f; bins[g][2]=0.f; }

        #pragma unroll
        for (int vx = 0; vx < 8; ++vx) {
            const float f  = fv[vx];
            const float wx = k2 ? (float)vx*0.125f : 1.f - (float)vx*0.125f;
            const float u0 = (float)U0[vx] * wx;
            const float u1 = (float)U1[vx] * wx;
            const float u2 = (float)U2[vx] * wx;
            #pragma unroll
            for (int g = 0; g < 10; ++g) {
                const float w = fmaxf(1.f - fabsf(f - (float)g), 0.f);
                bins[g][0] += w*u0; bins[g][1] += w*u1; bins[g][2] += w*u2;
            }
        }
        _Float16* pA = sA + row*180 + k2*90;
        #pragma unroll
        for (int g = 0; g < 10; ++g) {
            pA[g*9 + cb]     = (_Float16)bins[g][0];
            pA[g*9 + cb + 1] = (_Float16)bins[g][1];
            if (cgrp == 3) pA[g*9 + 8] = (_Float16)bins[g][2];
        }
    }
    __syncthreads();   // sU dead from here; sB may reuse its storage

    // ---- stage B: y-reduce. thread = (lz, j2, k2, c), 288 active ----
    if (tid < 288) {
        const int c   = tid % 9;
        const int k2  = (tid / 9) & 1;
        const int j2  = (tid / 18) & 1;
        const int lzo = tid / 36;          // 0..7
        float S[10];
        #pragma unroll
        for (int g = 0; g < 10; ++g) S[g] = 0.f;
        for (int ly2 = 0; ly2 < 8; ++ly2) {
            const float wy = j2 ? (float)ly2*0.125f : 1.f - (float)ly2*0.125f;
            const _Float16* pA = sA + (lzo*8 + ly2)*180 + k2*90;
            #pragma unroll
            for (int g = 0; g < 10; ++g) S[g] += wy * (float)pA[g*9 + c];
        }
        float* pB = sB + lzo*360 + j2*180 + k2*90;
        #pragma unroll
        for (int g = 0; g < 10; ++g) pB[g*9 + c] = S[g];
    }
    __syncthreads();

    // ---- stage C: z-reduce -> private part slot (coalesced, non-atomic) ----
    for (int item = tid; item < PART; item += 512) {
        const int t  = item / 90;          // corner: i2*4 + j2*2 + k2
        const int gc = item % 90;
        const int i2 = t >> 2, j2 = (t >> 1) & 1, k2 = t & 1;
        float acc = 0.f;
        #pragma unroll
        for (int lzo = 0; lzo < 8; ++lzo) {
            const float wz = i2 ? (float)lzo*0.125f : 1.f - (float)lzo*0.125f;
            acc += wz * sB[lzo*360 + j2*180 + k2*90 + gc];
        }
        part[(size_t)bid*PART + item] = acc;
    }
}

// ---------------------------------------------------------------------------
// Dispatch 2: blocks [0, XY_BLOCKS) Gaussian x+y slice pass (q = exp(lnq));
// blocks [XY_BLOCKS, XY_BLOCKS+GVB): gather part -> gridA.
// ---------------------------------------------------------------------------
__global__ __launch_bounds__(256)
void k_xy_gather(const half8* __restrict__ lnq, half8* __restrict__ dst,
                 const float* __restrict__ part, float* __restrict__ grid)
{
    __shared__ _Float16 sIn[PLANE];
    __shared__ _Float16 sX[PLANE];

    const int tid = threadIdx.x;

    if (blockIdx.x >= XY_BLOCKS) {
        // ---- gather per-cell partials from <=8 contributing blocks ----
        const int item = (blockIdx.x - XY_BLOCKS)*256 + tid;
        if (item >= GOUT) return;
        const int c    = item % 9;
        const int cell = item / 9;
        const int gz = cell / ST0;
        int r = cell % ST0;
        const int gy = r / ST1;  r %= ST1;
        const int gx = r / ST2;
        const int g  = r % ST2;
        float acc = 0.f;
        #pragma unroll
        for (int t = 0; t < 8; ++t) {
            const int i2 = t >> 2, j2 = (t >> 1) & 1, k2 = t & 1;
            const int bz = gz - i2, by = gy - j2, bx = gx - k2;
            if ((unsigned)bz < (unsigned)NBLK && (unsigned)by < (unsigned)NBLK &&
                (unsigned)bx < (unsigned)NBLK)
                acc += part[(size_t)((bz*NBLK + by)*NBLK + bx)*PART + t*90 + g*9 + c];
        }
        grid[cell*CH + c] = acc;
        return;
    }

    // ---- Gaussian x+y over one (label,z) slice held in LDS ----
    half8* sIn8 = (half8*)sIn;
    half8* sX8  = (half8*)sX;
    const size_t base8 = (size_t)blockIdx.x * PLANE8;

    // stage: q = exp(lnq)
    for (int i = tid; i < PLANE8; i += 256) {
        const half8 v = lnq[base8 + i];
        half8 w;
        #pragma unroll
        for (int e = 0; e < 8; ++e) w[e] = (_Float16)__expf((float)v[e]);
        sIn8[i] = w;
    }
    __syncthreads();

    // x-blur: item = row*6 + seg; outputs x = 16*seg .. 16*seg+15
    for (int it = tid; it < 576; it += 256) {
        const int seg = it % 6;
        const int row = it / 6;
        float w[48];
        #pragma unroll
        for (int k = 0; k < 6; ++k) {
            const int j8 = 2*seg - 2 + k;
            half8 v = h8zero();
            if (j8 >= 0 && j8 < ROW8) v = sIn8[row*ROW8 + j8];
            #pragma unroll
            for (int e = 0; e < 8; ++e) w[k*8 + e] = (float)v[e];
        }
        half8 o0 = h8zero(), o1 = h8zero();
        #pragma unroll
        for (int i = 0; i < 16; ++i) {
            float acc = 0.f;
            #pragma unroll
            for (int t = -9; t <= 9; ++t) acc += GW[t < 0 ? -t : t] * w[i + 16 + t];
            if (i < 8) o0[i] = (_Float16)acc; else o1[i - 8] = (_Float16)acc;
        }
        sX8[row*ROW8 + 2*seg]     = o0;
        sX8[row*ROW8 + 2*seg + 1] = o1;
    }
    __syncthreads();

    // y-blur: item = yseg*12 + x8; outputs y = 4*yseg .. 4*yseg+3
    for (int it = tid; it < 288; it += 256) {
        const int x8   = it % ROW8;
        const int yseg = it / ROW8;
        const int ct = yseg * 4;
        float acc[4][8];
        #pragma unroll
        for (int k = 0; k < 4; ++k)
            #pragma unroll
            for (int e = 0; e < 8; ++e) acc[k][e] = 0.f;
        #pragma unroll
        for (int jj = 0; jj < 22; ++jj) {
            const int j = ct - 9 + jj;
            if (j < 0 || j >= DIM) continue;
            const half8 v = sX8[j*ROW8 + x8];
            float f[8];
            #pragma unroll
            for (int e = 0; e < 8; ++e) f[e] = (float)v[e];
            #pragma unroll
            for (int k = 0; k < 4; ++k) {
                const int d = jj - 9 - k;
                if (d >= -9 && d <= 9) {
                    const float wgt = GW[d < 0 ? -d : d];
                    #pragma unroll
                    for (int e = 0; e < 8; ++e) acc[k][e] += wgt * f[e];
                }
            }
        }
        #pragma unroll
        for (int k = 0; k < 4; ++k) {
            half8 o;
            #pragma unroll
            for (int e = 0; e < 8; ++e) o[e] = (_Float16)acc[k][e];
            dst[base8 + (ct + k)*ROW8 + x8] = o;
        }
    }
}

// ---------------------------------------------------------------------------
// Dispatch 3: blocks [0, Z_BLOCKS) Gaussian z-pass (g1 -> sp); blocks
// [Z_BLOCKS, Z_BLOCKS+GVB): 81-tap 4-D grid blur (gridA -> gridB).
// ---------------------------------------------------------------------------
__global__ __launch_bounds__(256)
void k_z_blur(const half8* __restrict__ src, half8* __restrict__ dst,
              const float* __restrict__ gsrc, float* __restrict__ gdst)
{
    const int tid = threadIdx.x;

    if (blockIdx.x >= Z_BLOCKS) {
        // ---- 81-tap 4-D [1,2,1]/4 blur over the L2-resident grid ----
        const int item = (blockIdx.x - Z_BLOCKS)*256 + tid;
        if (item >= GOUT) return;
        const int c    = item % 9;
        const int cell = item / 9;
        const int gz = cell / ST0;
        int r = cell % ST0;
        const int gy = r / ST1;  r %= ST1;
        const int gx = r / ST2;
        const int g  = r % ST2;

        const int crd[4] = {gz, gy, gx, g};
        const int ext[4] = {GD0, GD1, GD2, GD3};
        const int str[4] = {ST0, ST1, ST2, 1};
        float wa[4][3];
        int   oa[4][3];
        #pragma unroll
        for (int ax = 0; ax < 4; ++ax)
            #pragma unroll
            for (int dd = 0; dd < 3; ++dd) {
                const int cc = crd[ax] + dd - 1;
                const bool ok = (cc >= 0 && cc < ext[ax]);
                wa[ax][dd] = ok ? (dd == 1 ? 0.5f : 0.25f) : 0.f;
                oa[ax][dd] = ok ? (dd - 1) * str[ax] : 0;
            }

        float acc = 0.f;
        #pragma unroll
        for (int a = 0; a < 3; ++a) {
            const float w0 = wa[0][a];
            #pragma unroll
            for (int b = 0; b < 3; ++b) {
                const float w1 = w0 * wa[1][b];
                #pragma unroll
                for (int d2 = 0; d2 < 3; ++d2) {
                    const float w2 = w1 * wa[2][d2];
                    const int ob = oa[0][a] + oa[1][b] + oa[2][d2];
                    #pragma unroll
                    for (int e = 0; e < 3; ++e)
                        acc += w2 * wa[3][e] * gsrc[(cell + ob + oa[3][e])*CH + c];
                }
            }
        }
        gdst[cell*CH + c] = acc;
        return;
    }

    // ---- Gaussian z-pass: thread owns 8 x-halves x 4 outputs along z ----
    const int bid = blockIdx.x;
    const int swz = (bid & 7) * (Z_BLOCKS >> 3) + (bid >> 3);
    const int u = swz * 256 + tid;

    const int x8 = u % ROW8;
    const int yy = (u / ROW8) % DIM;
    const int ztl = u / (ROW8 * DIM);       // zt + 24*l
    const int zt = ztl % (DIM/4);
    const int l  = ztl / (DIM/4);
    const int base8 = l * VOL8 + yy * ROW8 + x8;
    const int ct = zt * 4;

    float acc[4][8];
    #pragma unroll
    for (int k = 0; k < 4; ++k)
        #pragma unroll
        for (int e = 0; e < 8; ++e) acc[k][e] = 0.f;

    #pragma unroll
    for (int jj = 0; jj < 22; ++jj) {
        const int j = ct - 9 + jj;
        if (j < 0 || j >= DIM) continue;
        const half8 v = src[base8 + j*PLANE8];
        float f[8];
        #pragma unroll
        for (int e = 0; e < 8; ++e) f[e] = (float)v[e];
        #pragma unroll
        for (int k = 0; k < 4; ++k) {
            const int d = jj - 9 - k;
            if (d >= -9 && d <= 9) {
                const float wgt = GW[d < 0 ? -d : d];
                #pragma unroll
                for (int e = 0; e < 8; ++e) acc[k][e] += wgt * f[e];
            }
        }
    }
    #pragma unroll
    for (int k = 0; k < 4; ++k) {
        half8 o;
        #pragma unroll
        for (int e = 0; e < 8; ++e) o[e] = (_Float16)acc[k][e];
        dst[base8 + (ct + k)*PLANE8] = o;
    }
}

// ---------------------------------------------------------------------------
// Final: block = 32x16x1 voxels (512 thr, z BLOCK-UNIFORM).
// LDS-staged z-prereduced grid footprint; reads lnq fp16 + sp fp16 coalesced;
// out = softmax(lnq + Qp) == softmax(U + Qp).
// ---------------------------------------------------------------------------
__global__ __launch_bounds__(512)
void k_final(const _Float16* __restrict__ lnq, const _Float16* __restrict__ sp,
             const float* __restrict__ grid, const float* __restrict__ img,
             const float* __restrict__ Cm, const float* __restrict__ Sw,
             const float* __restrict__ Bw, float* __restrict__ out)
{
    __shared__ float sm[128];
    __shared__ __align__(16) float sG[1800];   // [yc3][xc5][g10][c12]

    const int tid = threadIdx.x;
    if (tid < 64) {
        const int i = tid >> 3, j = tid & 7;
        float cs = 0.f, cb = 0.f;
        #pragma unroll
        for (int k = 0; k < 8; ++k) {
            cs += Cm[i*8 + k] * Sw[k*8 + j];
            cb += Cm[i*8 + k] * Bw[k*8 + j];
        }
        sm[tid] = cs;
        sm[64 + tid] = cb;
    }

    const int bid0 = blockIdx.x;
    const int bid = (bid0 & 7) * (1728 >> 3) + (bid0 >> 3);   // XCD-chunk swizzle
    const int bxi = bid % 3;
    const int byi = (bid / 3) % 6;
    const int z   = bid / 18;            // 0..95 (uniform per block)

    const int zc0 = z >> 3;
    const float fz = (float)(z & 7) * 0.125f;

    // stage z-prereduced grid footprint (grid is L2-resident)
    for (int item = tid; item < 1800; item += 512) {
        const int c    = item % 12;
        const int cell = item / 12;        // yc*50 + xc*10 + g
        const int g  = cell % 10;
        const int xc = (cell / 10) % 5;
        const int yc = cell / 50;
        const int cellA = zc0*ST0 + (byi*2 + yc)*ST1 + (bxi*4 + xc)*ST2 + g;
        sG[item] = (1.f - fz)*grid[cellA*CH + c] + fz*grid[(cellA + ST0)*CH + c];
    }
    __syncthreads();

    const int lx  = tid & 31;
    const int lyt = tid >> 5;            // 0..15
    const int x = bxi*32 + lx;
    const int y = byi*16 + lyt;
    const int vox = z*PLANE + y*DIM + x;

    const float f = img[vox] * 8.0f;
    int li = (int)floorf(f);
    li = li < 0 ? 0 : (li > 8 ? 8 : li);
    const float fi = f - (float)li;
    const float fy = (float)(y & 7) * 0.125f;
    const float fx = (float)(x & 7) * 0.125f;
    const float wyv[2] = {1.f - fy, fy};
    const float wxv[2] = {1.f - fx, fx};
    const float wiv[2] = {1.f - fi, fi};
    const int ycb = lyt >> 3;            // 0..1
    const int xcb = lx >> 3;             // 0..3

    float acc[9];
    #pragma unroll
    for (int c = 0; c < 9; ++c) acc[c] = 0.f;

    #pragma unroll
    for (int j2 = 0; j2 < 2; ++j2)
    #pragma unroll
    for (int k2 = 0; k2 < 2; ++k2) {
        const float wsp = wyv[j2] * wxv[k2];
        const int base = (((ycb + j2)*5 + (xcb + k2))*10 + li)*12;
        #pragma unroll
        for (int m2 = 0; m2 < 2; ++m2) {
            const float w = wsp * wiv[m2];
            const float* p = &sG[base + m2*12];
            const float4 p0 = *reinterpret_cast<const float4*>(p);
            const float4 p1 = *reinterpret_cast<const float4*>(p + 4);
            acc[0] += w * p0.x; acc[1] += w * p0.y; acc[2] += w * p0.z; acc[3] += w * p0.w;
            acc[4] += w * p1.x; acc[5] += w * p1.y; acc[6] += w * p1.z; acc[7] += w * p1.w;
            acc[8] += w * p[8];
        }
    }
    const float dinv = 1.f / (acc[8] + 1e-8f);

    float spv[LBL], lq[LBL];
    #pragma unroll
    for (int l = 0; l < LBL; ++l) {
        spv[l] = (float)sp[(size_t)l*NVOX + vox];
        lq[l]  = (float)lnq[(size_t)l*NVOX + vox];
    }

    float v[LBL];
    float mx = -1e30f;
    #pragma unroll
    for (int i = 0; i < LBL; ++i) {
        float t = 0.f;
        #pragma unroll
        for (int l = 0; l < LBL; ++l)
            t += sm[i*8 + l] * spv[l] + sm[64 + i*8 + l] * (acc[l] * dinv);
        v[i] = lq[i] + t;
        mx = fmaxf(mx, v[i]);
    }
    float ssum = 0.f;
    #pragma unroll
    for (int i = 0; i < LBL; ++i) { v[i] = __expf(v[i] - mx); ssum += v[i]; }
    const float inv = 1.f / ssum;
    #pragma unroll
    for (int i = 0; i < LBL; ++i) out[i*NVOX + vox] = v[i] * inv;
}

extern "C" void kernel_launch(void* const* d_in, const int* in_sizes, int n_in,
                              void* d_out, int out_size, void* d_ws, size_t ws_size,
                              hipStream_t stream)
{
    const float* U   = (const float*)d_in[0];
    const float* img = (const float*)d_in[1];
    const float* Sw  = (const float*)d_in[2];
    const float* Bw  = (const float*)d_in[3];
    const float* Cm  = (const float*)d_in[4];
    float* out = (float*)d_out;

    _Float16* qh  = (_Float16*)d_ws;                       // lnq: 8*NVOX halves
    _Float16* g1h = qh  + (size_t)LBL * NVOX;              // xy-out: 8*NVOX halves
    _Float16* g2h = g1h + (size_t)LBL * NVOX;              // sp: 8*NVOX halves
    float* gridA  = (float*)(g2h + (size_t)LBL * NVOX);    // GSIZE*CH floats
    float* gridB  = gridA + (size_t)GSIZE * CH;            // GSIZE*CH floats
    float* part   = gridB + (size_t)GSIZE * CH;            // NBLKS*PART floats

    k_softmax_splat<<<NBLKS, 512, 0, stream>>>(U, img, qh, part);

    k_xy_gather<<<XY_BLOCKS + GVB, 256, 0, stream>>>(
        (const half8*)qh, (half8*)g1h, part, gridA);

    k_z_blur<<<Z_BLOCKS + GVB, 256, 0, stream>>>(
        (const half8*)g1h, (half8*)g2h, gridA, gridB);

    k_final<<<1728, 512, 0, stream>>>(qh, (const _Float16*)g2h,
                                      gridB, img, Cm, Sw, Bw, out);
}